// Round 5
// baseline (598.880 us; speedup 1.0000x reference)
//
#include <hip/hip_runtime.h>
#include <math.h>

// ---------------------------------------------------------------------------
// TbDNet forward, round 5:
//  - stem1p: conflict-free staging (4ic x 4px register transpose, b64 writes)
//  - fc1p: LDS-staged W tile (coalesced 256B row runs, prefetch, bf16 MFMA)
// ---------------------------------------------------------------------------

typedef __attribute__((ext_vector_type(8)))  short   short8;
typedef __attribute__((ext_vector_type(8)))  __bf16  bf16x8;
typedef __attribute__((ext_vector_type(4)))  float   f32x4;

#define NROUNDS 15
#define NKS 49          // fc1 K-splits (KC = 50176/49 = 1024)

// byte offsets in ws
#define B_WSTEM1 0UL                 // bf16 [9][128][1024]
#define B_WSTEM2 2359296UL           // bf16 [9][128][128]
#define B_WMOD   2654208UL           // 9 x bf16 [9][128][128]
#define B_WCLS   5308416UL           // bf16 [1024][128]
#define B_STEM   5570560UL           // bf16 [64][196][128]
#define B_XA     8781824UL
#define B_XB     11993088UL
#define B_FEAT   15204352UL
#define B_ATTN   18415616UL          // f32 [64][196]
#define B_SAVED  18465792UL
#define B_SCHED  18515968UL          // int [64][NROUNDS]
#define B_ACTB   18520064UL          // bf16 permuted fc1-B, 6422528 B
#define B_FC1T   24942592UL          // f32 [1024][64]
// overlays:
#define B_S1P    B_XB                // stem1 partials bf16 [4][64][196][128] = 12845056 B
#define B_FC1P   B_STEM              // fc1 partials f32 [49][1024][64] = 12845056 B

__device__ __forceinline__ unsigned short f2bf(float f) {
    unsigned int b = __float_as_uint(f);
    b += 0x7fffu + ((b >> 16) & 1u);          // RNE
    return (unsigned short)(b >> 16);
}
__device__ __forceinline__ float bf2f(unsigned short u) {
    return __uint_as_float(((unsigned int)u) << 16);
}
__device__ __forceinline__ f32x4 mfma16(bf16x8 a, bf16x8 b, f32x4 c) {
    return __builtin_amdgcn_mfma_f32_16x16x32_bf16(a, b, c, 0, 0, 0);
}

// ---------------------------------------------------------------------------
// Weight repack: conv sets -> [tap][oc][ic] bf16; cls_w -> straight bf16.
// ---------------------------------------------------------------------------
struct RepackArgs { const float* src[12]; };

__global__ __launch_bounds__(256) void k_repack(RepackArgs a, char* ws)
{
    const int y = blockIdx.y;
    const float* __restrict__ src = a.src[y];
    int gid = blockIdx.x * 256 + threadIdx.x;
    int gsz = gridDim.x * 256;
    if (y == 11) {
        unsigned short* dst = (unsigned short*)(ws + B_WCLS);
        for (int i = gid; i < 131072; i += gsz) dst[i] = f2bf(src[i]);
    } else {
        const int IC = (y == 0) ? 1024 : 128;
        const int lg = (y == 0) ? 10 : 7;
        unsigned short* dst = (unsigned short*)(ws + ((y == 0) ? B_WSTEM1
                                    : (y == 1) ? B_WSTEM2
                                    : B_WMOD + (size_t)(y - 2) * 294912));
        const int total = 9 << (lg + 7);
        for (int i = gid; i < total; i += gsz) {
            int ic = i & (IC - 1);
            int oc = (i >> lg) & 127;
            int t  = i >> (lg + 7);
            dst[i] = f2bf(src[((size_t)oc * IC + ic) * 9 + t]);
        }
    }
}

// ---------------------------------------------------------------------------
// Program decode + state init (runs AFTER stem1r; FEAT overlays stem1 partials)
// ---------------------------------------------------------------------------
__global__ __launch_bounds__(256) void k_decode_init(const int* __restrict__ prog, char* ws)
{
    int gid = blockIdx.x * 256 + threadIdx.x;
    int gsz = gridDim.x * 256;
    float* attn  = (float*)(ws + B_ATTN);
    float* saved = (float*)(ws + B_SAVED);
    for (int i = gid; i < 64 * 196; i += gsz) { attn[i] = 1.0f; saved[i] = 1.0f; }
    unsigned int* fz = (unsigned int*)(ws + B_FEAT);
    for (int i = gid; i < 64 * 25088 / 2; i += gsz) fz[i] = 0u;
    if (gid < 64) {
        int n = gid;
        int ent[NROUNDS];
        for (int r = 0; r < NROUNDS; ++r) ent[r] = 0;
        int rc = 0;
#define ENC(op,wv,dl,g,s,d) ((op)|((wv)<<4)|((dl)<<8)|((g)<<12)|((s)<<13)|((d)<<15))
#define EMIT(v) do { if (rc < NROUNDS) ent[rc++] = (v); } while (0)
        for (int j = 7; j >= 0; --j) {
            int t = prog[n * 8 + j];
            switch (t) {
                case 3: EMIT(ENC(1,0,0,0,0,0)); break;  // SCENE
                case 4: EMIT(ENC(2,0,0,0,0,0)); break;  // INTERSECT
                case 5:                                  // FILT
                    EMIT(ENC(3,0,1,1,3,0));
                    EMIT(ENC(3,1,1,0,0,1));
                    EMIT(ENC(4,0,0,0,1,0));
                    break;
                case 6:                                  // RELATE
                    EMIT(ENC(3,2,1,1,3,0));
                    EMIT(ENC(3,3,2,0,0,1));
                    EMIT(ENC(3,4,4,0,1,0));
                    EMIT(ENC(3,5,8,0,0,1));
                    EMIT(ENC(3,6,1,0,1,0));
                    EMIT(ENC(4,1,0,0,0,0));
                    break;
                case 7:                                  // QUERY
                    EMIT(ENC(3,7,1,1,3,0));
                    EMIT(ENC(3,8,1,0,0,2));
                    break;
                default: break;
            }
        }
#undef EMIT
#undef ENC
        int* sched = (int*)(ws + B_SCHED);
        for (int r = 0; r < NROUNDS; ++r) sched[n * NROUNDS + r] = ent[r];
    }
}

// ---------------------------------------------------------------------------
// stem1 partial conv: block = (n, ks 0..3, och, pxh). 2 slabs of 128 ic each.
// Staging: thread owns a 4ic x 4px block -> register transpose -> b64 writes
// (ic-major lane spread => ~2-way bank alias only). MFMA loop: plain chunks.
// ---------------------------------------------------------------------------
__global__ __launch_bounds__(256) void k_stem1p(const float* __restrict__ feats,
                                                const unsigned short* __restrict__ wrep,
                                                char* ws)
{
    __shared__ unsigned short s_img[197 * 136];
    const int bx = blockIdx.x;
    const int n = bx >> 4, ks = (bx >> 2) & 3, och = (bx >> 1) & 1, pxh = bx & 1;
    const int tid = threadIdx.x, lane = tid & 63;
    const int w = tid >> 6, wm = w & 1, wn = w >> 1;
    const int l15 = lane & 15, lq = lane >> 4;

    if (tid < 68) ((unsigned int*)s_img)[196 * 68 + tid] = 0u;   // zero row

    int pglob[4], pbyt[4], pyv[4], pxv[4];
#pragma unroll
    for (int j = 0; j < 4; ++j) {
        int nt = wn + 2 * j;
        int p  = (pxh * 7 + nt) * 16 + l15;
        pglob[j] = p;
        int py = p / 14;
        pyv[j] = (p < 196) ? py : 10000;
        pxv[j] = p - py * 14;
        pbyt[j] = p * 272 + lq * 16;
    }
    const int zaddr = 196 * 272 + lq * 16;
    const int nNT = (wn == 0) ? 4 : 3;

    f32x4 acc[2][4];
#pragma unroll
    for (int m = 0; m < 2; ++m)
#pragma unroll
        for (int j = 0; j < 4; ++j) acc[m][j] = (f32x4){0.f, 0.f, 0.f, 0.f};

    const int icg = tid & 31;          // 4-ic group within slab

    for (int slab = 0; slab < 2; ++slab) {
        if (slab) __syncthreads();
        const int icb = ks * 256 + slab * 128;
        const float* sf = feats + ((size_t)n * 1024 + icb) * 196;
        for (int qq = (tid >> 5); qq < 49; qq += 8) {
            const float* p0 = sf + icg * 4 * 196 + qq * 4;
            float4 r0 = *(const float4*)(p0);
            float4 r1 = *(const float4*)(p0 + 196);
            float4 r2 = *(const float4*)(p0 + 392);
            float4 r3 = *(const float4*)(p0 + 588);
#pragma unroll
            for (int e = 0; e < 4; ++e) {
                uint2 v;
                v.x = (unsigned int)f2bf(((const float*)&r0)[e]) |
                      ((unsigned int)f2bf(((const float*)&r1)[e]) << 16);
                v.y = (unsigned int)f2bf(((const float*)&r2)[e]) |
                      ((unsigned int)f2bf(((const float*)&r3)[e]) << 16);
                *(uint2*)(s_img + (qq * 4 + e) * 136 + icg * 4) = v;
            }
        }
        __syncthreads();

#pragma unroll
        for (int t = 0; t < 9; ++t) {
            const int dy = t / 3 - 1, dx = t % 3 - 1;
            int baddr[4];
#pragma unroll
            for (int j = 0; j < 4; ++j) {
                int yy = pyv[j] + dy, xx = pxv[j] + dx;
                bool ok = ((unsigned)yy < 14u) && ((unsigned)xx < 14u);
                baddr[j] = ok ? (pbyt[j] + (dy * 14 + dx) * 272) : zaddr;
            }
#pragma unroll
            for (int kc = 0; kc < 4; ++kc) {
                const unsigned short* wt = wrep +
                    ((size_t)(t * 128 + och * 64 + wm * 32 + l15) * 1024 + icb + kc * 32 + lq * 8);
                bf16x8 a0 = *(const bf16x8*)(wt);
                bf16x8 a1 = *(const bf16x8*)(wt + 16 * 1024);
#pragma unroll
                for (int j = 0; j < 4; ++j) {
                    if (j < nNT) {
                        bf16x8 b = *(const bf16x8*)((const char*)s_img + baddr[j] + kc * 64);
                        acc[0][j] = mfma16(a0, b, acc[0][j]);
                        acc[1][j] = mfma16(a1, b, acc[1][j]);
                    }
                }
            }
        }
    }

    // write bf16 partials: part[ks][n][p][oc]
    unsigned short* part = (unsigned short*)(ws + B_S1P);
#pragma unroll
    for (int m = 0; m < 2; ++m) {
        const int oc = och * 64 + wm * 32 + m * 16 + lq * 4;
#pragma unroll
        for (int j = 0; j < 4; ++j) {
            if (j < nNT) {
                int p = pglob[j];
                if (p < 196) {
                    unsigned int lo = (unsigned int)f2bf(acc[m][j][0]) |
                                      ((unsigned int)f2bf(acc[m][j][1]) << 16);
                    unsigned int hi = (unsigned int)f2bf(acc[m][j][2]) |
                                      ((unsigned int)f2bf(acc[m][j][3]) << 16);
                    uint2 pk; pk.x = lo; pk.y = hi;
                    *(uint2*)(part + (((size_t)ks * 64 + n) * 196 + p) * 128 + oc) = pk;
                }
            }
        }
    }
}

// stem1 reduce: sum 4 bf16 partials + bias + relu -> XA bf16 [n][p][128]
__global__ __launch_bounds__(256) void k_stem1r(const char* __restrict__ ws_c,
                                                const float* __restrict__ bias,
                                                unsigned short* __restrict__ xa)
{
    int i = blockIdx.x * 256 + threadIdx.x;        // 64*196*16
    const unsigned short* part = (const unsigned short*)(ws_c + B_S1P);
    int oc8 = (i & 15) * 8;
    int np  = i >> 4;                               // n*196+p
    float s[8] = {};
#pragma unroll
    for (int ks = 0; ks < 4; ++ks) {
        short8 v = *(const short8*)(part + (((size_t)ks * 64) * 196 + np) * 128 + oc8);
#pragma unroll
        for (int e = 0; e < 8; ++e) s[e] += bf2f((unsigned short)v[e]);
    }
    short8 o;
#pragma unroll
    for (int e = 0; e < 8; ++e)
        o[e] = (short)f2bf(fmaxf(s[e] + bias[oc8 + e], 0.f));
    *(short8*)(xa + (size_t)np * 128 + oc8) = o;
}

// ---------------------------------------------------------------------------
// MFMA 3x3 dilated conv core for 128-IC (stem2 + module rounds).
// ---------------------------------------------------------------------------
__device__ void conv_mfma_core(const unsigned short* __restrict__ srcB,
                               const float*  __restrict__ gate,
                               const unsigned short* __restrict__ wrep,
                               const float*  __restrict__ bias,
                               unsigned short* __restrict__ dst,
                               int dil, int och, int pxh,
                               unsigned short* s_img)
{
    const int tid  = threadIdx.x, lane = tid & 63;
    const int w    = tid >> 6, wm = w & 1, wn = w >> 1;
    const int l15  = lane & 15, lq = lane >> 4;

    if (tid < 68) ((unsigned int*)s_img)[196 * 68 + tid] = 0u;   // zero page row

    int pglob[4], pbyt[4], pyv[4], pxv[4];
#pragma unroll
    for (int j = 0; j < 4; ++j) {
        int nt = wn + 2 * j;
        int p  = (pxh * 7 + nt) * 16 + l15;
        pglob[j] = p;
        int py = p / 14;
        pyv[j] = (p < 196) ? py : 10000;
        pxv[j] = p - py * 14;
        pbyt[j] = p * 272 + lq * 16;
    }
    const int zaddr = 196 * 272 + lq * 16;
    const int nNT = (wn == 0) ? 4 : 3;

    f32x4 acc[2][4];
#pragma unroll
    for (int m = 0; m < 2; ++m)
#pragma unroll
        for (int j = 0; j < 4; ++j) acc[m][j] = (f32x4){0.f, 0.f, 0.f, 0.f};

    if (gate) {
        for (int i = tid; i < 196 * 16; i += 256) {
            int p = i >> 4, c8 = (i & 15) * 8;
            short8 v = *(const short8*)(srcB + p * 128 + c8);
            float g = gate[p];
            short8 ov;
#pragma unroll
            for (int e = 0; e < 8; ++e)
                ov[e] = (short)f2bf(bf2f((unsigned short)v[e]) * g);
            *(short8*)(s_img + p * 136 + c8) = ov;
        }
    } else {
        for (int i = tid; i < 196 * 16; i += 256) {
            int p = i >> 4, c8 = (i & 15) * 8;
            *(short8*)(s_img + p * 136 + c8) = *(const short8*)(srcB + p * 128 + c8);
        }
    }
    __syncthreads();

    const unsigned short* wlane = wrep + (size_t)(och * 64 + wm * 32 + l15) * 128 + lq * 8;
#pragma unroll
    for (int t = 0; t < 9; ++t) {
        const int dy = (t / 3 - 1) * dil, dx = (t % 3 - 1) * dil;
        int baddr[4];
#pragma unroll
        for (int j = 0; j < 4; ++j) {
            int yy = pyv[j] + dy, xx = pxv[j] + dx;
            bool ok = ((unsigned)yy < 14u) && ((unsigned)xx < 14u);
            baddr[j] = ok ? (pbyt[j] + (dy * 14 + dx) * 272) : zaddr;
        }
        const unsigned short* wt = wlane + (size_t)(t * 128) * 128;
#pragma unroll
        for (int kc = 0; kc < 4; ++kc) {
            bf16x8 a0 = *(const bf16x8*)(wt + kc * 32);
            bf16x8 a1 = *(const bf16x8*)(wt + (size_t)16 * 128 + kc * 32);
#pragma unroll
            for (int j = 0; j < 4; ++j) {
                if (j < nNT) {
                    bf16x8 b = *(const bf16x8*)((const char*)s_img + baddr[j] + kc * 64);
                    acc[0][j] = mfma16(a0, b, acc[0][j]);
                    acc[1][j] = mfma16(a1, b, acc[1][j]);
                }
            }
        }
    }

    // epilogue: bias + relu -> bf16 [196][128]
#pragma unroll
    for (int m = 0; m < 2; ++m) {
        const int oc = och * 64 + wm * 32 + m * 16 + lq * 4;
        const float4 b4 = *(const float4*)(bias + oc);
#pragma unroll
        for (int j = 0; j < 4; ++j) {
            if (j < nNT) {
                int p = pglob[j];
                if (p < 196) {
                    float v0 = fmaxf(acc[m][j][0] + b4.x, 0.f);
                    float v1 = fmaxf(acc[m][j][1] + b4.y, 0.f);
                    float v2 = fmaxf(acc[m][j][2] + b4.z, 0.f);
                    float v3 = fmaxf(acc[m][j][3] + b4.w, 0.f);
                    unsigned int lo = (unsigned int)f2bf(v0) | ((unsigned int)f2bf(v1) << 16);
                    unsigned int hi = (unsigned int)f2bf(v2) | ((unsigned int)f2bf(v3) << 16);
                    uint2 pk; pk.x = lo; pk.y = hi;
                    *(uint2*)(dst + p * 128 + oc) = pk;
                }
            }
        }
    }
}

__global__ __launch_bounds__(256) void k_conv_stem2(const unsigned short* __restrict__ srcBall,
                                                    const unsigned short* __restrict__ wrep,
                                                    const float* __restrict__ bias,
                                                    unsigned short* __restrict__ dstall)
{
    __shared__ unsigned short s_img[197 * 136];
    const int n = blockIdx.x >> 2, och = (blockIdx.x >> 1) & 1, pxh = blockIdx.x & 1;
    conv_mfma_core(srcBall + (size_t)n * 25088, nullptr, wrep, bias,
                   dstall + (size_t)n * 25088, 1, och, pxh, s_img);
}

// ---------------------------------------------------------------------------
// Module interpreter round.
// ---------------------------------------------------------------------------
struct RArgs {
    char* ws;
    const float* mbias[9];
    const float* w1x1[2];
    const float* b1x1[2];
};

__global__ __launch_bounds__(256) void k_round(RArgs a, int r)
{
    __shared__ unsigned short s_img[197 * 136];
    const int bx = blockIdx.x;
    const int n = bx >> 2, och = (bx >> 1) & 1, pxh = bx & 1;
    char* ws = a.ws;
    const int* sched = (const int*)(ws + B_SCHED);
    const int e = sched[n * NROUNDS + r];
    const int op = e & 15;
    if (op == 0) return;
    float* attn  = (float*)(ws + B_ATTN)  + n * 196;
    float* saved = (float*)(ws + B_SAVED) + n * 196;
    if (op == 1 || op == 2) {
        if ((bx & 3) == 0 && threadIdx.x < 196) {
            int p = threadIdx.x;
            if (op == 1) { saved[p] = attn[p]; attn[p] = 1.0f; }
            else         attn[p] = fminf(attn[p], saved[p]);
        }
        return;
    }
    const int wset = (e >> 4) & 15, dil = (e >> 8) & 15, gatef = (e >> 12) & 1;
    const int srcid = (e >> 13) & 3, dstid = (e >> 15) & 3;
    const unsigned short* src = (const unsigned short*)(ws +
            (srcid == 3 ? B_STEM : srcid == 1 ? B_XB : B_XA)) + (size_t)n * 25088;
    if (op == 4) {                                  // conv1x1 + sigmoid -> attn
        if ((bx & 3) == 0 && threadIdx.x < 196) {
            int p = threadIdx.x;
            const float* wv = a.w1x1[wset];
            float acc = a.b1x1[wset][0];
            const unsigned short* row = src + p * 128;
#pragma unroll 8
            for (int ic = 0; ic < 128; ++ic) acc += bf2f(row[ic]) * wv[ic];
            attn[p] = 1.0f / (1.0f + __expf(-acc));
        }
        return;
    }
    unsigned short* dst = (unsigned short*)(ws +
            (dstid == 2 ? B_FEAT : dstid == 1 ? B_XB : B_XA)) + (size_t)n * 25088;
    const unsigned short* wrep = (const unsigned short*)(ws + B_WMOD) + (size_t)wset * 9 * 128 * 128;
    conv_mfma_core(src, gatef ? attn : nullptr, wrep, a.mbias[wset], dst,
                   dil, och, pxh, s_img);
}

// ---------------------------------------------------------------------------
// cls 1x1 conv (128->1024, MFMA) + bias + relu + 2x2 maxpool -> actB bf16
// permuted fc1-B layout: k -> kb=k>>6, lq2=(k>>4)&3, hi=(k>>3)&1, e=k&7
// offset = (((kb*4+lq2)*2+hi)*64 + n)*8 + e.
// ---------------------------------------------------------------------------
__global__ __launch_bounds__(256) void k_cls_pool(const unsigned short* __restrict__ featall,
                                                  const unsigned short* __restrict__ clsw,
                                                  const float* __restrict__ clsb,
                                                  unsigned short* __restrict__ actB)
{
    __shared__ char smem[197 * 272 + 64 * 200 * 4];
    unsigned short* s_img = (unsigned short*)smem;
    float* s_pool = (float*)(smem + 197 * 272);
    const int n = blockIdx.x >> 4, pt = blockIdx.x & 15;
    const int tid = threadIdx.x, lane = tid & 63, w = tid >> 6;
    const int l15 = lane & 15, lq = lane >> 4;
    const unsigned short* feat = featall + (size_t)n * 25088;

    if (tid < 68) ((unsigned int*)s_img)[196 * 68 + tid] = 0u;
    for (int i = tid; i < 196 * 16; i += 256) {
        int p = i >> 4, c8 = (i & 15) * 8;
        *(short8*)(s_img + p * 136 + c8) = *(const short8*)(feat + p * 128 + c8);
    }
    f32x4 acc[14];
#pragma unroll
    for (int j = 0; j < 14; ++j) acc[j] = (f32x4){0.f, 0.f, 0.f, 0.f};
    __syncthreads();

    const unsigned short* wl = clsw + (size_t)(pt * 64 + w * 16 + l15) * 128 + lq * 8;
#pragma unroll
    for (int kc = 0; kc < 4; ++kc) {
        bf16x8 a0 = *(const bf16x8*)(wl + kc * 32);
#pragma unroll
        for (int j = 0; j < 14; ++j) {
            int p = j * 16 + l15;
            int ba = (p < 196) ? (p * 272 + lq * 16 + kc * 64) : (196 * 272 + lq * 16);
            bf16x8 b = *(const bf16x8*)((const char*)s_img + ba);
            acc[j] = mfma16(a0, b, acc[j]);
        }
    }
    const int oc = pt * 64 + w * 16 + lq * 4;
    const float4 b4 = *(const float4*)(clsb + oc);
    const int pl = w * 16 + lq * 4;
#pragma unroll
    for (int j = 0; j < 14; ++j) {
        int p = j * 16 + l15;
        if (p < 196) {
            s_pool[(pl + 0) * 200 + p] = fmaxf(acc[j][0] + b4.x, 0.f);
            s_pool[(pl + 1) * 200 + p] = fmaxf(acc[j][1] + b4.y, 0.f);
            s_pool[(pl + 2) * 200 + p] = fmaxf(acc[j][2] + b4.z, 0.f);
            s_pool[(pl + 3) * 200 + p] = fmaxf(acc[j][3] + b4.w, 0.f);
        }
    }
    __syncthreads();
    for (int i = tid; i < 64 * 49; i += 256) {
        int plx = i / 49, q = i - plx * 49;
        int py = q / 7, qx = q - py * 7;
        const float* rp = s_pool + plx * 200 + py * 28 + qx * 2;
        float m = fmaxf(fmaxf(rp[0], rp[1]), fmaxf(rp[14], rp[15]));
        int k = (pt * 64 + plx) * 49 + q;
        int kb = k >> 6, lq2 = (k >> 4) & 3, hi = (k >> 3) & 1, e = k & 7;
        actB[((((size_t)kb * 4 + lq2) * 2 + hi) * 64 + n) * 8 + e] = f2bf(m);
    }
}

// ---------------------------------------------------------------------------
// fc1 partial GEMM with LDS-staged W tile.
// Block = (ks 0..48, jt 0..15): j-tile 64, k-slice 1024 (4 stage steps of 256).
// Stage: thread (r4=tid&3, l4=(tid>>2)&15, rw=tid>>6): 4 passes x 4 float4 ->
//        16-lane 256B contiguous runs per row; convert bf16 -> s_w[64][264].
// ---------------------------------------------------------------------------
__global__ __launch_bounds__(256) void k_fc1p(const unsigned short* __restrict__ actB,
                                              const float* __restrict__ w,
                                              float* __restrict__ part)
{
    __shared__ unsigned short s_w[64 * 264];       // 33792 B
    const int jt = blockIdx.x & 15, ks = blockIdx.x >> 4;
    const int tid = threadIdx.x, lane = tid & 63, wv = tid >> 6;
    const int l15 = lane & 15, lq = lane >> 4;
    const int k0 = ks * 1024;
    const int r4 = tid & 3, l4 = (tid >> 2) & 15, rw = tid >> 6;

    f32x4 acc[4];
#pragma unroll
    for (int t = 0; t < 4; ++t) acc[t] = (f32x4){0.f, 0.f, 0.f, 0.f};

    float4 pf[4][4];

#define FC1_LOAD(ss_) do {                                                        \
    _Pragma("unroll")                                                             \
    for (int pass = 0; pass < 4; ++pass) {                                        \
        const int row_ = pass * 16 + rw * 4 + r4;                                 \
        const float* wp_ = w + (size_t)(jt * 64 + row_) * 50176 + k0              \
                             + (ss_) * 256 + l4 * 16;                             \
        pf[pass][0] = *(const float4*)(wp_);                                      \
        pf[pass][1] = *(const float4*)(wp_ + 4);                                  \
        pf[pass][2] = *(const float4*)(wp_ + 8);                                  \
        pf[pass][3] = *(const float4*)(wp_ + 12);                                 \
    } } while (0)

    FC1_LOAD(0);

    for (int ss = 0; ss < 4; ++ss) {
        __syncthreads();                            // previous compute done
#pragma unroll
        for (int pass = 0; pass < 4; ++pass) {
            const int row = pass * 16 + rw * 4 + r4;
            bf16x8 c0, c1;
            c0[0] = (__bf16)pf[pass][0].x; c0[1] = (__bf16)pf[pass][0].y;
            c0[2] = (__bf16)pf[pass][0].z; c0[3] = (__bf16)pf[pass][0].w;
            c0[4] = (__bf16)pf[pass][1].x; c0[5] = (__bf16)pf[pass][1].y;
            c0[6] = (__bf16)pf[pass][1].z; c0[7] = (__bf16)pf[pass][1].w;
            c1[0] = (__bf16)pf[pass][2].x; c1[1] = (__bf16)pf[pass][2].y;
            c1[2] = (__bf16)pf[pass][2].z; c1[3] = (__bf16)pf[pass][2].w;
            c1[4] = (__bf16)pf[pass][3].x; c1[5] = (__bf16)pf[pass][3].y;
            c1[6] = (__bf16)pf[pass][3].z; c1[7] = (__bf16)pf[pass][3].w;
            *(bf16x8*)(s_w + row * 264 + l4 * 16)     = c0;
            *(bf16x8*)(s_w + row * 264 + l4 * 16 + 8) = c1;
        }
        __syncthreads();
        if (ss < 3) FC1_LOAD(ss + 1);               // prefetch under compute

        const unsigned short* arow = s_w + (wv * 16 + l15) * 264;
#pragma unroll
        for (int kk = 0; kk < 8; ++kk) {
            bf16x8 a = *(const bf16x8*)(arow + kk * 32 + lq * 8);
            const int kglob = k0 + ss * 256 + kk * 32 + lq * 8;
            const int kb = kglob >> 6, lq2 = (kglob >> 4) & 3, hi = (kglob >> 3) & 1;
            const unsigned short* bp = actB +
                ((((size_t)kb * 4 + lq2) * 2 + hi) * 64 + l15) * 8;
#pragma unroll
            for (int t = 0; t < 4; ++t) {
                bf16x8 b = *(const bf16x8*)(bp + t * 128);
                acc[t] = mfma16(a, b, acc[t]);
            }
        }
    }
#undef FC1_LOAD

    float* pbase = part + ((size_t)ks * 1024 + jt * 64 + wv * 16 + lq * 4) * 64 + l15;
#pragma unroll
    for (int t = 0; t < 4; ++t)
#pragma unroll
        for (int r = 0; r < 4; ++r)
            pbase[(size_t)r * 64 + t * 16] = acc[t][r];
}

__global__ __launch_bounds__(256) void k_fc1r(const float* __restrict__ part,
                                              const float* __restrict__ b,
                                              float* __restrict__ fc1T)
{
    int i = blockIdx.x * 256 + threadIdx.x;
    if (i >= 65536) return;
    float s = 0.0f;
    for (int ks = 0; ks < NKS; ++ks) s += part[(size_t)ks * 65536 + i];
    int j = i >> 6;
    fc1T[i] = fmaxf(s + b[j], 0.0f);
}

__global__ __launch_bounds__(256) void k_fc2(const float* __restrict__ fc1T,
                                             const float* __restrict__ w,
                                             const float* __restrict__ b,
                                             float* __restrict__ out)
{
    __shared__ float red[256];
    const int a_ = blockIdx.x;
    const int tid = threadIdx.x, lane = tid & 63, q = tid >> 6;
    float acc = 0.0f;
    const float* wr = w + (size_t)a_ * 1024;
    for (int k = q * 256; k < q * 256 + 256; ++k)
        acc = fmaf(fc1T[k * 64 + lane], wr[k], acc);
    red[tid] = acc;
    __syncthreads();
    if (q == 0) {
        float s = red[tid] + red[tid + 64] + red[tid + 128] + red[tid + 192] + b[a_];
        out[lane * 28 + a_] = s;
    }
}

extern "C" void kernel_launch(void* const* d_in, const int* in_sizes, int n_in,
                              void* d_out, int out_size, void* d_ws, size_t ws_size,
                              hipStream_t stream)
{
    const float* feats = (const float*)d_in[0];
    const int*   prog  = (const int*)d_in[1];
    char* ws  = (char*)d_ws;
    float* out = (float*)d_out;

    RepackArgs ra;
    ra.src[0]  = (const float*)d_in[2];   // stem_w1
    ra.src[1]  = (const float*)d_in[4];   // stem_w2
    ra.src[2]  = (const float*)d_in[6];   // att_w1
    ra.src[3]  = (const float*)d_in[8];   // att_w2
    ra.src[4]  = (const float*)d_in[12];  // rel_w1
    ra.src[5]  = (const float*)d_in[14];  // rel_w2
    ra.src[6]  = (const float*)d_in[16];  // rel_w3
    ra.src[7]  = (const float*)d_in[18];  // rel_w4
    ra.src[8]  = (const float*)d_in[20];  // rel_w5
    ra.src[9]  = (const float*)d_in[24];  // qry_w1
    ra.src[10] = (const float*)d_in[26];  // qry_w2
    ra.src[11] = (const float*)d_in[28];  // cls_w

    k_repack<<<dim3(64, 12), 256, 0, stream>>>(ra, ws);

    // stem1: feats(f32) -> partials -> XA
    k_stem1p<<<1024, 256, 0, stream>>>(feats, (const unsigned short*)(ws + B_WSTEM1), ws);
    k_stem1r<<<784, 256, 0, stream>>>(ws, (const float*)d_in[3],
                                      (unsigned short*)(ws + B_XA));

    k_decode_init<<<256, 256, 0, stream>>>(prog, ws);   // after stem1r (FEAT overlay)

    // stem2: XA -> STEM
    k_conv_stem2<<<256, 256, 0, stream>>>((const unsigned short*)(ws + B_XA),
                                          (const unsigned short*)(ws + B_WSTEM2),
                                          (const float*)d_in[5],
                                          (unsigned short*)(ws + B_STEM));

    RArgs ga;
    ga.ws = ws;
    ga.mbias[0] = (const float*)d_in[7];   // att_b1
    ga.mbias[1] = (const float*)d_in[9];   // att_b2
    ga.mbias[2] = (const float*)d_in[13];  // rel_b1
    ga.mbias[3] = (const float*)d_in[15];  // rel_b2
    ga.mbias[4] = (const float*)d_in[17];  // rel_b3
    ga.mbias[5] = (const float*)d_in[19];  // rel_b4
    ga.mbias[6] = (const float*)d_in[21];  // rel_b5
    ga.mbias[7] = (const float*)d_in[25];  // qry_b1
    ga.mbias[8] = (const float*)d_in[27];  // qry_b2
    ga.w1x1[0]  = (const float*)d_in[10];  // att_w3
    ga.w1x1[1]  = (const float*)d_in[22];  // rel_w6
    ga.b1x1[0]  = (const float*)d_in[11];  // att_b3
    ga.b1x1[1]  = (const float*)d_in[23];  // rel_b6

    for (int r = 0; r < NROUNDS; ++r)
        k_round<<<256, 256, 0, stream>>>(ga, r);

    k_cls_pool<<<1024, 256, 0, stream>>>((const unsigned short*)(ws + B_FEAT),
                                         (const unsigned short*)(ws + B_WCLS),
                                         (const float*)d_in[29],
                                         (unsigned short*)(ws + B_ACTB));
    k_fc1p<<<784, 256, 0, stream>>>((const unsigned short*)(ws + B_ACTB),
                                    (const float*)d_in[30], (float*)(ws + B_FC1P));
    k_fc1r<<<256, 256, 0, stream>>>((const float*)(ws + B_FC1P), (const float*)d_in[31],
                                    (float*)(ws + B_FC1T));
    k_fc2<<<28, 256, 0, stream>>>((const float*)(ws + B_FC1T), (const float*)d_in[32],
                                  (const float*)d_in[33], out);
}